// Round 5
// baseline (110.709 us; speedup 1.0000x reference)
//
#include <hip/hip_runtime.h>
#include <math.h>

#define WPB 4                 // waves per block; 2 rows per wave (one per 32-lane half)
#define BLOCK_T (WPB * 64)
#define GX 8
#define GY 8
#define GZ 16
#define NCELL (GX * GY * GZ)  // 1024 cells; z fastest => z-columns are CSR-contiguous
#define CAP 32                // candidate cap per row (fits one 32-lane half)
#define CELL_LDS 8192

__device__ __forceinline__ double d2_exact(float ax, float ay, float az,
                                           float bx, float by, float bz) {
    const double dx = (double)ax - (double)bx;
    const double dy = (double)ay - (double)by;
    const double dz = (double)az - (double)bz;
    return fma(dx, dx, fma(dy, dy, dz * dz));
}

__device__ __forceinline__ int cell_of(float x, float y, float z) {
    int cx = (int)floorf((x + 1.0f) * (GX * 0.5f)); cx = min(max(cx, 0), GX - 1);
    int cy = (int)floorf((y + 1.0f) * (GY * 0.5f)); cy = min(max(cy, 0), GY - 1);
    int cz = (int)floorf((z + 1.0f) * (GZ * 0.5f)); cz = min(max(cz, 0), GZ - 1);
    return (cx * GY + cy) * GZ + cz;
}

// Single-block fused grid build: LDS histogram -> LDS scan -> scatter.
__global__ __launch_bounds__(NCELL)
void k_build(const float* __restrict__ vp, float4* __restrict__ pts4,
             int* __restrict__ off, int Mv)
{
    __shared__ int s_cnt[NCELL];
    __shared__ int s_scan[NCELL];
    __shared__ int s_cell[CELL_LDS];
    const int t = threadIdx.x;
    s_cnt[t] = 0;
    __syncthreads();
    for (int j = t; j < Mv; j += NCELL) {
        const int c = cell_of(vp[3*j], vp[3*j+1], vp[3*j+2]);
        if (j < CELL_LDS) s_cell[j] = c;
        atomicAdd(&s_cnt[c], 1);
    }
    __syncthreads();
    const int c = s_cnt[t];
    s_scan[t] = c;
    __syncthreads();
    for (int d = 1; d < NCELL; d <<= 1) {
        const int v = (t >= d) ? s_scan[t - d] : 0;
        __syncthreads();
        s_scan[t] += v;
        __syncthreads();
    }
    const int start = s_scan[t] - c;
    off[t] = start;
    if (t == NCELL - 1) off[NCELL] = s_scan[t];
    s_cnt[t] = start;                    // becomes running cursor
    __syncthreads();
    for (int j = t; j < Mv; j += NCELL) {
        const float x = vp[3*j], y = vp[3*j+1], z = vp[3*j+2];
        const int cell = (j < CELL_LDS) ? s_cell[j] : cell_of(x, y, z);
        const int pos = atomicAdd(&s_cnt[cell], 1);
        pts4[pos] = make_float4(x, y, z, __int_as_float(j));
    }
}

// Two rows per wave (one per 32-lane half).
// Rows [0, Nq): per-query Voronoi edge-distance min  -> out[row]
// Rows [Nq, Nq+Mv): per-vpoint 10-NN repulsion       -> out[Nq + r*10 + j]
__global__ __launch_bounds__(BLOCK_T)
void voronoi_kernel(const float* __restrict__ queries,
                    const float* __restrict__ vpoints,
                    const float4* __restrict__ pts4,
                    const int* __restrict__ off,
                    float* __restrict__ out,
                    int Nq, int Mv)
{
    __shared__ int s_i[WPB][2][CAP];

    const int lane = threadIdx.x & 63;
    const int hl   = lane & 31;           // lane within half
    const int half = lane >> 5;
    const int wv   = threadIdx.x >> 6;
    const int row  = (blockIdx.x * WPB + wv) * 2 + half;
    const int total = Nq + Mv;
    if (row >= total) return;             // per-half exit; no barriers anywhere

    const bool  isq = (row < Nq);
    const float* src = isq ? (queries + 3 * row) : (vpoints + 3 * (row - Nq));
    const float qx = src[0], qy = src[1], qz = src[2];

    // ---- adaptive radius h: target ~21 candidates (window [11,32]), boundary-aware ----
    const float rho = (float)Mv * 0.125f;
    const float Tt  = 21.0f * 6.0f / (3.14159265f * rho);
    float h = 0.5f * cbrtf(Tt);
    #pragma unroll
    for (int it = 0; it < 2; ++it) {
        float ex = fminf(qx + h, 1.0f) - fmaxf(qx - h, -1.0f);
        float ey = fminf(qy + h, 1.0f) - fmaxf(qy - h, -1.0f);
        float ez = fminf(qz + h, 1.0f) - fmaxf(qz - h, -1.0f);
        h *= cbrtf(Tt / (ex * ey * ez));
    }

    // ---- grid-pruned scan + per-half ballot-compact into LDS ----
    // strict count (fp32 d2 < tau=h^2) >= 11 proves the true fp64 top-11 are all
    // admitted by the loose test (MARGIN covers fp32-vs-fp64 boundary error);
    // cntL <= 32 proves none were dropped. Rescan steps (cube 2.0 / 0.512) cannot
    // jump the [11,32] window (ratio 2.9).
    const float MARGIN = 2e-5f;
    int cntS = 0, cntL = 0;
    for (int attempt = 0; attempt < 16; ++attempt) {
        cntS = 0; cntL = 0;
        const float tau  = h * h;
        const float tauL = tau + MARGIN;
        int ix0 = (int)floorf((qx - h + 1.0f) * (GX * 0.5f)); ix0 = min(max(ix0, 0), GX - 1);
        int ix1 = (int)floorf((qx + h + 1.0f) * (GX * 0.5f)); ix1 = min(max(ix1, 0), GX - 1);
        int iy0 = (int)floorf((qy - h + 1.0f) * (GY * 0.5f)); iy0 = min(max(iy0, 0), GY - 1);
        int iy1 = (int)floorf((qy + h + 1.0f) * (GY * 0.5f)); iy1 = min(max(iy1, 0), GY - 1);
        int iz0 = (int)floorf((qz - h + 1.0f) * (GZ * 0.5f)); iz0 = min(max(iz0, 0), GZ - 1);
        int iz1 = (int)floorf((qz + h + 1.0f) * (GZ * 0.5f)); iz1 = min(max(iz1, 0), GZ - 1);

        for (int cx = ix0; cx <= ix1; ++cx) {
            for (int cy = iy0; cy <= iy1; ++cy) {
                const int colbase = (cx * GY + cy) * GZ;
                const int s0 = off[colbase + iz0];      // z-contiguous CSR range
                const int e0 = off[colbase + iz1 + 1];
                for (int p0 = s0; p0 < e0; p0 += 32) {  // trip count uniform per half
                    const int p = p0 + hl;
                    bool ps = false, pl = false;
                    int  pid = 0;
                    if (p < e0) {
                        const float4 pt = pts4[p];
                        const float dx = qx - pt.x, dy = qy - pt.y, dz = qz - pt.z;
                        const float d2 = fmaf(dx, dx, fmaf(dy, dy, dz * dz));
                        pid = __float_as_int(pt.w);
                        ps = (d2 < tau);
                        pl = (d2 < tauL);
                    }
                    const unsigned long long mS64 = __ballot(ps);
                    const unsigned long long mL64 = __ballot(pl);
                    const unsigned mS = (unsigned)(mS64 >> (half << 5));
                    const unsigned mL = (unsigned)(mL64 >> (half << 5));
                    if (pl) {
                        const int o = cntL + (int)__popc(mL & ((1u << hl) - 1u));
                        if (o < CAP) s_i[wv][half][o] = pid;
                    }
                    cntS += (int)__popc(mS);
                    cntL += (int)__popc(mL);
                }
            }
        }
        if (cntS >= 11 && cntL <= CAP) break;           // uniform per half
        h *= (cntS < 11) ? 1.26f : 0.80f;               // count scales ~h^3
    }

    // ---- one candidate/lane: recompute d2 in fp64 (exact ordering) ----
    double d  = 1e300;
    int    id = 0x40000000 + lane;          // unique pad ids (> any real id)
    if (hl < cntL) {
        id = s_i[wv][half][hl];
        const float* b = vpoints + 3 * id;
        d = d2_exact(qx, qy, qz, b[0], b[1], b[2]);
    }

    // ---- 32-lane bitonic sort (per half) ascending on (d, id); strides <= 16
    //      stay intra-half; direction uses hl so BOTH halves sort ascending. ----
    #pragma unroll
    for (int k = 2; k <= 32; k <<= 1) {
        #pragma unroll
        for (int jj = k >> 1; jj > 0; jj >>= 1) {
            const double od = __shfl_xor(d, jj, 64);
            const int    oi = __shfl_xor(id, jj, 64);
            const bool pless    = (od < d) || (od == d && oi < id);
            const bool want_min = (((hl & k) == 0) == ((hl & jj) == 0));
            const bool take     = (pless == want_min);
            d  = take ? od : d;
            id = take ? oi : id;
        }
    }
    // lane hl holds the (hl+1)-th smallest (d, id) of its half's row.

    if (isq) {
        const int   idx0 = __shfl(id, half << 5, 64);   // half's lane 0
        const float p0x = vpoints[3 * idx0];
        const float p0y = vpoints[3 * idx0 + 1];
        const float p0z = vpoints[3 * idx0 + 2];
        float sq = INFINITY;
        if (hl >= 1 && hl <= 10) {
            const float vx = vpoints[3 * id], vy = vpoints[3 * id + 1], vz = vpoints[3 * id + 2];
            const float ex = vx - p0x, ey = vy - p0y, ez = vz - p0z;
            const float el = sqrtf(ex * ex + ey * ey + ez * ez);
            const float px = qx - p0x, py = qy - p0y, pz = qz - p0z;
            const float vl = (px * ex + py * ey + pz * ez) / el;
            const float t  = vl - 0.5f * el;
            sq = t * t;
        }
        #pragma unroll
        for (int s = 16; s > 0; s >>= 1) sq = fminf(sq, __shfl_xor(sq, s, 64));
        if (hl == 0) out[row] = sq;
    } else {
        if (hl >= 1 && hl <= 10) {
            const float v = (float)d;
            out[Nq + (row - Nq) * 10 + (hl - 1)] = expf(-100.0f * v) / 100.0f;
        }
    }
}

extern "C" void kernel_launch(void* const* d_in, const int* in_sizes, int n_in,
                              void* d_out, int out_size, void* d_ws, size_t ws_size,
                              hipStream_t stream) {
    const float* queries = (const float*)d_in[0];
    const float* vpoints = (const float*)d_in[1];
    float* out = (float*)d_out;
    const int Nq = in_sizes[0] / 3;
    const int Mv = in_sizes[1] / 3;

    // workspace layout: pts4[Mv] | off[NCELL+1]
    char* base = (char*)d_ws;
    float4* pts4 = (float4*)base;
    int* off = (int*)(base + (size_t)Mv * sizeof(float4));

    k_build<<<1, NCELL, 0, stream>>>(vpoints, pts4, off, Mv);

    const int total_rows = Nq + Mv;
    const int rows_per_block = WPB * 2;
    const int blocks = (total_rows + rows_per_block - 1) / rows_per_block;
    voronoi_kernel<<<blocks, BLOCK_T, 0, stream>>>(queries, vpoints, pts4, off,
                                                   out, Nq, Mv);
}

// Round 6
// 86.011 us; speedup vs baseline: 1.2871x; 1.2871x over previous
//
#include <hip/hip_runtime.h>
#include <math.h>

#define WPB 4                 // waves per block; ONE row per full 64-lane wave
#define BLOCK_T (WPB * 64)
#define GX 8
#define GY 8
#define GZ 16
#define NCELL (GX * GY * GZ)  // 1024 cells; z fastest => z-columns are CSR-contiguous
#define CAP 64                // candidate cap per row
#define CELL_LDS 8192
#define IDMASK 8191ull        // low 13 bits of sort key hold the point id (Mv < 8192)

__device__ __forceinline__ float fast_cbrt(float x) {
    // x > 0. Bit-hack seed (~3% rel) + 1 Newton step (~0.2% rel) — plenty for
    // radius targeting (count ~ h^3 -> ~0.6% count error).
    float y = __int_as_float(0x2a514067 + __float_as_int(x) / 3);
    y = 0.33333333f * (2.0f * y + x * __frcp_rn(y * y));
    return y;
}

__device__ __forceinline__ int cell_of(float x, float y, float z) {
    int cx = (int)floorf((x + 1.0f) * (GX * 0.5f)); cx = min(max(cx, 0), GX - 1);
    int cy = (int)floorf((y + 1.0f) * (GY * 0.5f)); cy = min(max(cy, 0), GY - 1);
    int cz = (int)floorf((z + 1.0f) * (GZ * 0.5f)); cz = min(max(cz, 0), GZ - 1);
    return (cx * GY + cy) * GZ + cz;
}

// Single-block fused grid build: LDS histogram -> LDS scan -> scatter.
__global__ __launch_bounds__(NCELL)
void k_build(const float* __restrict__ vp, float4* __restrict__ pts4,
             int* __restrict__ off, int Mv)
{
    __shared__ int s_cnt[NCELL];
    __shared__ int s_scan[NCELL];
    __shared__ int s_cell[CELL_LDS];
    const int t = threadIdx.x;
    s_cnt[t] = 0;
    __syncthreads();
    for (int j = t; j < Mv; j += NCELL) {
        const int c = cell_of(vp[3*j], vp[3*j+1], vp[3*j+2]);
        if (j < CELL_LDS) s_cell[j] = c;
        atomicAdd(&s_cnt[c], 1);
    }
    __syncthreads();
    const int c = s_cnt[t];
    s_scan[t] = c;
    __syncthreads();
    for (int d = 1; d < NCELL; d <<= 1) {
        const int v = (t >= d) ? s_scan[t - d] : 0;
        __syncthreads();
        s_scan[t] += v;
        __syncthreads();
    }
    const int start = s_scan[t] - c;
    off[t] = start;
    if (t == NCELL - 1) off[NCELL] = s_scan[t];
    s_cnt[t] = start;                    // becomes running cursor
    __syncthreads();
    for (int j = t; j < Mv; j += NCELL) {
        const float x = vp[3*j], y = vp[3*j+1], z = vp[3*j+2];
        const int cell = (j < CELL_LDS) ? s_cell[j] : cell_of(x, y, z);
        const int pos = atomicAdd(&s_cnt[cell], 1);
        pts4[pos] = make_float4(x, y, z, __int_as_float(j));
    }
}

// One full wave per output row.
// Rows [0, Nq): per-query Voronoi edge-distance min  -> out[row]
// Rows [Nq, Nq+Mv): per-vpoint 10-NN repulsion       -> out[Nq + r*10 + j]
__global__ __launch_bounds__(BLOCK_T)
void voronoi_kernel(const float* __restrict__ queries,
                    const float* __restrict__ vpoints,
                    const float4* __restrict__ pts4,
                    const int* __restrict__ off,
                    float* __restrict__ out,
                    int Nq, int Mv)
{
    __shared__ int s_i[WPB][CAP];

    const int lane = threadIdx.x & 63;
    const int wv   = threadIdx.x >> 6;
    const int row  = blockIdx.x * WPB + wv;
    const int total = Nq + Mv;
    if (row >= total) return;             // wave-uniform

    const bool  isq = (row < Nq);
    const float* src = isq ? (queries + 3 * row) : (vpoints + 3 * (row - Nq));
    const float qx = src[0], qy = src[1], qz = src[2];

    // ---- adaptive radius h: target ~26 strict candidates, boundary-aware ----
    const float rho = (float)Mv * 0.125f;
    const float Tt  = 26.0f * 6.0f / (3.14159265f * rho);
    float h = 0.5f * fast_cbrt(Tt);
    #pragma unroll
    for (int it = 0; it < 2; ++it) {
        float ex = fminf(qx + h, 1.0f) - fmaxf(qx - h, -1.0f);
        float ey = fminf(qy + h, 1.0f) - fmaxf(qy - h, -1.0f);
        float ez = fminf(qz + h, 1.0f) - fmaxf(qz - h, -1.0f);
        h *= fast_cbrt(Tt * __frcp_rn(ex * ey * ez));
    }

    // ---- grid-pruned scan + ballot-compact candidate ids into wave LDS ----
    // strict count (fp32 d2 < tau=h^2) >= 11 proves the true fp64 top-11 all pass
    // the loose test (MARGIN >> fp32 d2 error); cntL <= CAP proves none dropped.
    // Rescan factors (count x2.46 / x0.512) cannot jump the [11,64] window (5.8x).
    const float MARGIN = 2e-5f;
    int cntS = 0, cntL = 0;
    for (int attempt = 0; attempt < 16; ++attempt) {
        cntS = 0; cntL = 0;
        const float tau  = h * h;
        const float tauL = tau + MARGIN;
        int ix0 = (int)floorf((qx - h + 1.0f) * (GX * 0.5f)); ix0 = min(max(ix0, 0), GX - 1);
        int ix1 = (int)floorf((qx + h + 1.0f) * (GX * 0.5f)); ix1 = min(max(ix1, 0), GX - 1);
        int iy0 = (int)floorf((qy - h + 1.0f) * (GY * 0.5f)); iy0 = min(max(iy0, 0), GY - 1);
        int iy1 = (int)floorf((qy + h + 1.0f) * (GY * 0.5f)); iy1 = min(max(iy1, 0), GY - 1);
        int iz0 = (int)floorf((qz - h + 1.0f) * (GZ * 0.5f)); iz0 = min(max(iz0, 0), GZ - 1);
        int iz1 = (int)floorf((qz + h + 1.0f) * (GZ * 0.5f)); iz1 = min(max(iz1, 0), GZ - 1);
        // wave-uniform -> move loop control to SALU
        ix0 = __builtin_amdgcn_readfirstlane(ix0);
        ix1 = __builtin_amdgcn_readfirstlane(ix1);
        iy0 = __builtin_amdgcn_readfirstlane(iy0);
        iy1 = __builtin_amdgcn_readfirstlane(iy1);
        iz0 = __builtin_amdgcn_readfirstlane(iz0);
        iz1 = __builtin_amdgcn_readfirstlane(iz1);

        for (int cx = ix0; cx <= ix1; ++cx) {
            for (int cy = iy0; cy <= iy1; ++cy) {
                const int colbase = (cx * GY + cy) * GZ;
                const int s0 = __builtin_amdgcn_readfirstlane(off[colbase + iz0]);
                const int e0 = __builtin_amdgcn_readfirstlane(off[colbase + iz1 + 1]);
                for (int p0 = s0; p0 < e0; p0 += 64) {  // wave-uniform trip count
                    const int p = p0 + lane;
                    bool ps = false, pl = false;
                    int  pid = 0;
                    if (p < e0) {
                        const float4 pt = pts4[p];
                        const float dx = qx - pt.x, dy = qy - pt.y, dz = qz - pt.z;
                        const float d2 = fmaf(dx, dx, fmaf(dy, dy, dz * dz));
                        pid = __float_as_int(pt.w);
                        ps = (d2 < tau);
                        pl = (d2 < tauL);
                    }
                    const unsigned long long mS = __ballot(ps);
                    const unsigned long long mL = __ballot(pl);
                    if (pl) {
                        const int o = cntL + (int)__popcll(mL & ((1ULL << lane) - 1ULL));
                        if (o < CAP) s_i[wv][o] = pid;
                    }
                    cntS += (int)__popcll(mS);
                    cntL += (int)__popcll(mL);
                }
            }
        }
        if (cntS >= 11 && cntL <= CAP) break;           // wave-uniform
        h *= (cntS < 11) ? 1.35f : 0.80f;               // count scales ~h^3
    }

    // ---- packed sort key: fp64 d2 bits with low 13 mantissa bits = id ----
    // Positive-double bit patterns are order-monotone as u64. Clearing 13 bits
    // perturbs d2 by rel 2^-39; if two cleared keys collide, id order == the
    // reference's stable-top_k tie order. Pad lanes get the max key.
    unsigned long long key = ~0ull;
    if (lane < cntL) {
        const int id = s_i[wv][lane];
        const float* b = vpoints + 3 * id;
        const double dx = (double)qx - (double)b[0];
        const double dy = (double)qy - (double)b[1];
        const double dz = (double)qz - (double)b[2];
        const double d2 = fma(dx, dx, fma(dy, dy, dz * dz));
        key = (__double_as_longlong(d2) & ~IDMASK) | (unsigned long long)id;
    }

    // ---- bitonic sort ascending on u64 key; 15 stages if cntL<=32 (~95%) ----
    if (cntL <= 32) {
        const int hl = lane & 31;         // strides <=16 stay intra-half; both
        #pragma unroll                    // halves sort ascending (lanes 32+: pads)
        for (int k = 2; k <= 32; k <<= 1) {
            #pragma unroll
            for (int jj = k >> 1; jj > 0; jj >>= 1) {
                const unsigned long long ok = __shfl_xor(key, jj, 64);
                const bool want_min = (((hl & k) == 0) == ((hl & jj) == 0));
                if ((ok < key) == want_min) key = ok;
            }
        }
    } else {
        #pragma unroll
        for (int k = 2; k <= 64; k <<= 1) {
            #pragma unroll
            for (int jj = k >> 1; jj > 0; jj >>= 1) {
                const unsigned long long ok = __shfl_xor(key, jj, 64);
                const bool want_min = (((lane & k) == 0) == ((lane & jj) == 0));
                if ((ok < key) == want_min) key = ok;
            }
        }
    }
    // lane l (l<=10) now holds the (l+1)-th smallest key; ranks 0..10 = 11-NN.

    if (isq) {
        const int idx0 = (int)(__shfl(key, 0, 64) & IDMASK);
        const float p0x = vpoints[3 * idx0];
        const float p0y = vpoints[3 * idx0 + 1];
        const float p0z = vpoints[3 * idx0 + 2];
        float sq = INFINITY;
        if (lane >= 1 && lane <= 10) {
            const int id = (int)(key & IDMASK);
            const float vx = vpoints[3 * id], vy = vpoints[3 * id + 1], vz = vpoints[3 * id + 2];
            const float ex = vx - p0x, ey = vy - p0y, ez = vz - p0z;
            const float el = sqrtf(ex * ex + ey * ey + ez * ez);
            const float px = qx - p0x, py = qy - p0y, pz = qz - p0z;
            const float vl = (px * ex + py * ey + pz * ez) / el;
            const float t  = vl - 0.5f * el;
            sq = t * t;
        }
        #pragma unroll
        for (int s = 32; s > 0; s >>= 1) sq = fminf(sq, __shfl_xor(sq, s, 64));
        if (lane == 0) out[row] = sq;
    } else {
        if (lane >= 1 && lane <= 10) {
            const double d2s = __longlong_as_double((long long)(key & ~IDMASK));
            const float v = (float)d2s;   // matches ref f32 d2 to ~1e-7
            out[Nq + (row - Nq) * 10 + (lane - 1)] = expf(-100.0f * v) / 100.0f;
        }
    }
}

extern "C" void kernel_launch(void* const* d_in, const int* in_sizes, int n_in,
                              void* d_out, int out_size, void* d_ws, size_t ws_size,
                              hipStream_t stream) {
    const float* queries = (const float*)d_in[0];
    const float* vpoints = (const float*)d_in[1];
    float* out = (float*)d_out;
    const int Nq = in_sizes[0] / 3;
    const int Mv = in_sizes[1] / 3;

    // workspace layout: pts4[Mv] | off[NCELL+1]
    char* base = (char*)d_ws;
    float4* pts4 = (float4*)base;
    int* off = (int*)(base + (size_t)Mv * sizeof(float4));

    k_build<<<1, NCELL, 0, stream>>>(vpoints, pts4, off, Mv);

    const int total_rows = Nq + Mv;
    const int blocks = (total_rows + WPB - 1) / WPB;
    voronoi_kernel<<<blocks, BLOCK_T, 0, stream>>>(queries, vpoints, pts4, off,
                                                   out, Nq, Mv);
}

// Round 7
// 85.146 us; speedup vs baseline: 1.3002x; 1.0102x over previous
//
#include <hip/hip_runtime.h>
#include <math.h>

#define WPB 4                 // waves per block; ONE row per full 64-lane wave
#define BLOCK_T (WPB * 64)
#define GX 8
#define GY 8
#define GZ 16
#define NCELL (GX * GY * GZ)  // 1024 cells; z fastest => z-columns are CSR-contiguous
#define CAP 64                // candidate cap per row
#define IDMASK 8191ull        // low 13 bits of sort key hold the point id (Mv < 8192)

__device__ __forceinline__ float fast_cbrt(float x) {
    // x > 0. Bit-hack seed + 1 Newton step (~0.2% rel) — count ~ h^3 -> ~0.6% err.
    float y = __int_as_float(0x2a514067 + __float_as_int(x) / 3);
    y = 0.33333333f * (2.0f * y + x * __frcp_rn(y * y));
    return y;
}

__device__ __forceinline__ int cell_of(float x, float y, float z) {
    int cx = (int)floorf((x + 1.0f) * (GX * 0.5f)); cx = min(max(cx, 0), GX - 1);
    int cy = (int)floorf((y + 1.0f) * (GY * 0.5f)); cy = min(max(cy, 0), GY - 1);
    int cz = (int)floorf((z + 1.0f) * (GZ * 0.5f)); cz = min(max(cz, 0), GZ - 1);
    return (cx * GY + cy) * GZ + cz;
}

// ---- parallel grid build: memset(cnt) -> hist -> scan -> scatter ----
__global__ void k_hist(const float* __restrict__ vp, int* __restrict__ cnt, int Mv) {
    const int j = blockIdx.x * blockDim.x + threadIdx.x;
    if (j < Mv) atomicAdd(&cnt[cell_of(vp[3*j], vp[3*j+1], vp[3*j+2])], 1);
}

__global__ __launch_bounds__(NCELL)
void k_scan(const int* __restrict__ cnt, int* __restrict__ off, int* __restrict__ cur) {
    // 1024 threads = 16 waves; wave-shuffle scan, only 2 barriers.
    __shared__ int wsum[16];
    const int t = threadIdx.x, lane = t & 63, w = t >> 6;
    const int c = cnt[t];
    int v = c;
    #pragma unroll
    for (int s = 1; s < 64; s <<= 1) {
        const int u = __shfl_up(v, s, 64);
        if (lane >= s) v += u;
    }
    if (lane == 63) wsum[w] = v;
    __syncthreads();
    if (w == 0 && lane < 16) {
        int x = wsum[lane];
        #pragma unroll
        for (int s = 1; s < 16; s <<= 1) {
            const int u = __shfl_up(x, s, 64);
            if (lane >= s) x += u;
        }
        wsum[lane] = x;
    }
    __syncthreads();
    const int inc = v + ((w > 0) ? wsum[w - 1] : 0);
    off[t] = inc - c;
    cur[t] = inc - c;
    if (t == NCELL - 1) off[NCELL] = inc;
}

__global__ void k_scatter(const float* __restrict__ vp, int* __restrict__ cur,
                          float4* __restrict__ pts4, int Mv) {
    const int j = blockIdx.x * blockDim.x + threadIdx.x;
    if (j < Mv) {
        const float x = vp[3*j], y = vp[3*j+1], z = vp[3*j+2];
        const int pos = atomicAdd(&cur[cell_of(x, y, z)], 1);
        pts4[pos] = make_float4(x, y, z, __int_as_float(j));
    }
}

// One full wave per output row.
// Rows [0, Nq): per-query Voronoi edge-distance min  -> out[row]
// Rows [Nq, Nq+Mv): per-vpoint 10-NN repulsion       -> out[Nq + r*10 + j]
__global__ __launch_bounds__(BLOCK_T)
void voronoi_kernel(const float* __restrict__ queries,
                    const float* __restrict__ vpoints,
                    const float4* __restrict__ pts4,
                    const int* __restrict__ off,
                    float* __restrict__ out,
                    int Nq, int Mv)
{
    __shared__ float4             s_c[WPB][CAP];   // candidate coords + id
    __shared__ unsigned long long s_k[WPB][CAP];   // packed sort keys

    const int lane = threadIdx.x & 63;
    const int wv   = threadIdx.x >> 6;
    const int row  = blockIdx.x * WPB + wv;
    const int total = Nq + Mv;
    if (row >= total) return;             // wave-uniform

    const bool  isq = (row < Nq);
    const float* src = isq ? (queries + 3 * row) : (vpoints + 3 * (row - Nq));
    const float qx = src[0], qy = src[1], qz = src[2];

    // ---- adaptive radius h: target ~26 strict candidates, boundary-aware ----
    const float rho = (float)Mv * 0.125f;
    const float Tt  = 26.0f * 6.0f / (3.14159265f * rho);
    float h = 0.5f * fast_cbrt(Tt);
    #pragma unroll
    for (int it = 0; it < 2; ++it) {
        float ex = fminf(qx + h, 1.0f) - fmaxf(qx - h, -1.0f);
        float ey = fminf(qy + h, 1.0f) - fmaxf(qy - h, -1.0f);
        float ez = fminf(qz + h, 1.0f) - fmaxf(qz - h, -1.0f);
        h *= fast_cbrt(Tt * __frcp_rn(ex * ey * ez));
    }

    // ---- grid-pruned scan + ballot-compact (coords+id) into wave LDS ----
    // strict count (fp32 d2 < tau=h^2) >= 11 proves the true fp64 top-11 all pass
    // the loose test (MARGIN >> fp32 d2 error); cntL <= CAP proves none dropped.
    // Rescan factors (count x2.46 / x0.512) cannot jump the [11,64] window (5.8x).
    const float MARGIN = 2e-5f;
    int cntS = 0, cntL = 0;
    for (int attempt = 0; attempt < 16; ++attempt) {
        cntS = 0; cntL = 0;
        const float tau  = h * h;
        const float tauL = tau + MARGIN;
        int ix0 = (int)floorf((qx - h + 1.0f) * (GX * 0.5f)); ix0 = min(max(ix0, 0), GX - 1);
        int ix1 = (int)floorf((qx + h + 1.0f) * (GX * 0.5f)); ix1 = min(max(ix1, 0), GX - 1);
        int iy0 = (int)floorf((qy - h + 1.0f) * (GY * 0.5f)); iy0 = min(max(iy0, 0), GY - 1);
        int iy1 = (int)floorf((qy + h + 1.0f) * (GY * 0.5f)); iy1 = min(max(iy1, 0), GY - 1);
        int iz0 = (int)floorf((qz - h + 1.0f) * (GZ * 0.5f)); iz0 = min(max(iz0, 0), GZ - 1);
        int iz1 = (int)floorf((qz + h + 1.0f) * (GZ * 0.5f)); iz1 = min(max(iz1, 0), GZ - 1);
        // wave-uniform -> SALU loop control, s_load for off[]
        ix0 = __builtin_amdgcn_readfirstlane(ix0);
        ix1 = __builtin_amdgcn_readfirstlane(ix1);
        iy0 = __builtin_amdgcn_readfirstlane(iy0);
        iy1 = __builtin_amdgcn_readfirstlane(iy1);
        iz0 = __builtin_amdgcn_readfirstlane(iz0);
        iz1 = __builtin_amdgcn_readfirstlane(iz1);

        for (int cx = ix0; cx <= ix1; ++cx) {
            for (int cy = iy0; cy <= iy1; ++cy) {
                const int colbase = (cx * GY + cy) * GZ;
                const int s0 = __builtin_amdgcn_readfirstlane(off[colbase + iz0]);
                const int e0 = __builtin_amdgcn_readfirstlane(off[colbase + iz1 + 1]);
                for (int p0 = s0; p0 < e0; p0 += 64) {  // wave-uniform trip count
                    const int p = p0 + lane;
                    bool ps = false, pl = false;
                    float4 pt;
                    if (p < e0) {
                        pt = pts4[p];
                        const float dx = qx - pt.x, dy = qy - pt.y, dz = qz - pt.z;
                        const float d2 = fmaf(dx, dx, fmaf(dy, dy, dz * dz));
                        ps = (d2 < tau);
                        pl = (d2 < tauL);
                    }
                    const unsigned long long mS = __ballot(ps);
                    const unsigned long long mL = __ballot(pl);
                    if (pl) {
                        const int o = cntL + (int)__popcll(mL & ((1ULL << lane) - 1ULL));
                        if (o < CAP) s_c[wv][o] = pt;
                    }
                    cntS += (int)__popcll(mS);
                    cntL += (int)__popcll(mL);
                }
            }
        }
        if (cntS >= 11 && cntL <= CAP) break;           // wave-uniform
        h *= (cntS < 11) ? 1.35f : 0.80f;               // count scales ~h^3
    }
    cntL = min(cntL, CAP);                  // safety (attempt exhaustion only)

    // ---- packed key: fp64 d2 bits, low 13 mantissa bits = id (keys unique) ----
    float4 c4 = make_float4(0.f, 0.f, 0.f, 0.f);
    unsigned long long key = ~0ull;
    if (lane < cntL) {
        c4 = s_c[wv][lane];
        const double dx = (double)qx - (double)c4.x;
        const double dy = (double)qy - (double)c4.y;
        const double dz = (double)qz - (double)c4.z;
        const double d2 = fma(dx, dx, fma(dy, dy, dz * dz));
        key = (__double_as_longlong(d2) & ~IDMASK)
            | (unsigned long long)(unsigned)__float_as_int(c4.w);
    }

    // ---- rank-by-count: rank = #{keys < mine}; no dependent shuffle chain ----
    s_k[wv][lane] = key;
    int rank = 0;
    for (int c = 0; c < cntL; ++c)          // wave-uniform; broadcast ds_read
        rank += (s_k[wv][c] < key) ? 1 : 0;
    // real lanes get unique ranks 0..cntL-1; pad lanes rank >= cntL >= 11.

    if (isq) {
        // p0 = rank-0 candidate; edges = ranks 1..10 (set-min, order-free)
        const unsigned long long m0 = __ballot(rank == 0);
        const int l0 = (int)__ffsll((unsigned long long)m0) - 1;
        const float p0x = __shfl(c4.x, l0, 64);
        const float p0y = __shfl(c4.y, l0, 64);
        const float p0z = __shfl(c4.z, l0, 64);
        float sq = INFINITY;
        if (rank >= 1 && rank <= 10) {
            const float ex = c4.x - p0x, ey = c4.y - p0y, ez = c4.z - p0z;
            const float el = sqrtf(ex * ex + ey * ey + ez * ez);
            const float px = qx - p0x, py = qy - p0y, pz = qz - p0z;
            const float vl = (px * ex + py * ey + pz * ez) / el;
            const float t  = vl - 0.5f * el;
            sq = t * t;
        }
        #pragma unroll
        for (int s = 32; s > 0; s >>= 1) sq = fminf(sq, __shfl_xor(sq, s, 64));
        if (lane == 0) out[row] = sq;
    } else {
        if (rank >= 1 && rank <= 10) {
            const double d2s = __longlong_as_double((long long)(key & ~IDMASK));
            out[Nq + (row - Nq) * 10 + (rank - 1)] = expf(-100.0f * (float)d2s) / 100.0f;
        }
    }
}

extern "C" void kernel_launch(void* const* d_in, const int* in_sizes, int n_in,
                              void* d_out, int out_size, void* d_ws, size_t ws_size,
                              hipStream_t stream) {
    const float* queries = (const float*)d_in[0];
    const float* vpoints = (const float*)d_in[1];
    float* out = (float*)d_out;
    const int Nq = in_sizes[0] / 3;
    const int Mv = in_sizes[1] / 3;

    // workspace layout: pts4[Mv] | cnt[NCELL] | off[NCELL+1] | cur[NCELL]
    char* base = (char*)d_ws;
    float4* pts4 = (float4*)base;
    int* cnt = (int*)(base + (size_t)Mv * sizeof(float4));
    int* off = cnt + NCELL;
    int* cur = off + NCELL + 1;

    hipMemsetAsync(cnt, 0, NCELL * sizeof(int), stream);
    const int hb = (Mv + 255) / 256;
    k_hist<<<hb, 256, 0, stream>>>(vpoints, cnt, Mv);
    k_scan<<<1, NCELL, 0, stream>>>(cnt, off, cur);
    k_scatter<<<hb, 256, 0, stream>>>(vpoints, cur, pts4, Mv);

    const int total_rows = Nq + Mv;
    const int blocks = (total_rows + WPB - 1) / WPB;
    voronoi_kernel<<<blocks, BLOCK_T, 0, stream>>>(queries, vpoints, pts4, off,
                                                   out, Nq, Mv);
}